// Round 10
// baseline (816.610 us; speedup 1.0000x reference)
//
#include <hip/hip_runtime.h>

// GRU: B=256, T=1000, I=64, H=128.
// Round-10 = r8 ⊕ r9: 1024 threads (4 waves/SIMD, r8-validated latency
// hiding) + fp16 dot2 weights (r9-validated issue halving).
// tid = j*8+ks: j in [0,128) hidden unit, ks in [0,8) k-slice.
// Per-thread: 3 gate-rows x (8 W_hh pairs + 4 W_ih pairs) = 36 dot2/step.
// Evidence: r8 (1024thr fp32) VALUBusy 99.4% = issue-bound; r9 (512thr dot2)
// VALUBusy 60% = latency-bound. Combining attacks both measured walls.
// h carry stays fp32 (hbuf32); fp16 only inside dots. 1 barrier/step.
// 8-lane reduce: DPP quad xor1 (0xB1) + xor2 (0x4E) + row_half_mirror (0x141).

#define Bc 256
#define Tc 1000
#define Ic 64
#define Hc 128

typedef _Float16 f16x2 __attribute__((ext_vector_type(2)));

#if __has_builtin(__builtin_amdgcn_fdot2)
#define FDOT2(a, b, c) __builtin_amdgcn_fdot2((a), (b), (c), false)
#else
#define FDOT2(a, b, c) fmaf((float)(a).x, (float)(b).x, fmaf((float)(a).y, (float)(b).y, (c)))
#endif

__device__ __forceinline__ float fast_sigmoid(float x) {
    return __builtin_amdgcn_rcpf(1.0f + __expf(-x));
}
__device__ __forceinline__ float fast_tanh(float x) {
    return 1.0f - 2.0f * __builtin_amdgcn_rcpf(__expf(2.0f * x) + 1.0f);
}
template <int CTRL>
__device__ __forceinline__ float dpp_add(float x) {
    int y = __builtin_amdgcn_update_dpp(0, __float_as_int(x), CTRL, 0xF, 0xF, true);
    return x + __int_as_float(y);
}
// sum over the 8 lanes of an aligned 8-lane group
__device__ __forceinline__ float oct_reduce(float x) {
    x = dpp_add<0xB1>(x);    // + lane^1
    x = dpp_add<0x4E>(x);    // + lane^2
    x = dpp_add<0x141>(x);   // + lane^7 (row_half_mirror: other quad)
    return x;
}
__device__ __forceinline__ f16x2 pack2(float a, float b) {
    f16x2 r; r.x = (_Float16)a; r.y = (_Float16)b; return r;
}

__global__ __launch_bounds__(1024) void gru_scan_kernel(
    const float* __restrict__ input,   // [B][T][I]
    const float* __restrict__ W_ih,    // [3H][I]
    const float* __restrict__ W_hh,    // [3H][H]
    const float* __restrict__ b_ih,    // [3H]
    const float* __restrict__ b_hh,    // [3H]
    float* __restrict__ out)           // states [B][T][H] then hT [B][H]
{
    const int b   = blockIdx.x;
    const int tid = threadIdx.x;
    const int j   = tid >> 3;
    const int ks  = tid & 7;

    __shared__ __align__(16) _Float16 hbuf16[2][Hc];  // h as fp16 (dot operand)
    __shared__ float                  hbuf32[2][Hc];  // h carry, full fp32
    __shared__ __align__(16) _Float16 ibuf16[2][Ic];  // x row as fp16

    // ---- persistent weights, fp16-packed: 36 pair-regs/thread ----
    f16x2 wr[8], wz[8], wn[8];   // W_hh rows {j,H+j,2H+j}, cols [16ks,16ks+16)
    {
        const float4* pr = reinterpret_cast<const float4*>(W_hh + (size_t)j * Hc + ks * 16);
        const float4* pz = reinterpret_cast<const float4*>(W_hh + (size_t)(Hc + j) * Hc + ks * 16);
        const float4* pn = reinterpret_cast<const float4*>(W_hh + (size_t)(2 * Hc + j) * Hc + ks * 16);
#pragma unroll
        for (int q = 0; q < 4; ++q) {
            const float4 a = pr[q]; wr[2 * q] = pack2(a.x, a.y); wr[2 * q + 1] = pack2(a.z, a.w);
            const float4 c = pz[q]; wz[2 * q] = pack2(c.x, c.y); wz[2 * q + 1] = pack2(c.z, c.w);
            const float4 d = pn[q]; wn[2 * q] = pack2(d.x, d.y); wn[2 * q + 1] = pack2(d.z, d.w);
        }
    }
    f16x2 ur[4], uz[4], un[4];   // W_ih rows, cols [8ks,8ks+8)
    {
        const float4* pr = reinterpret_cast<const float4*>(W_ih + (size_t)j * Ic + ks * 8);
        const float4* pz = reinterpret_cast<const float4*>(W_ih + (size_t)(Hc + j) * Ic + ks * 8);
        const float4* pn = reinterpret_cast<const float4*>(W_ih + (size_t)(2 * Hc + j) * Ic + ks * 8);
#pragma unroll
        for (int q = 0; q < 2; ++q) {
            const float4 a = pr[q]; ur[2 * q] = pack2(a.x, a.y); ur[2 * q + 1] = pack2(a.z, a.w);
            const float4 c = pz[q]; uz[2 * q] = pack2(c.x, c.y); uz[2 * q + 1] = pack2(c.z, c.w);
            const float4 d = pn[q]; un[2 * q] = pack2(d.x, d.y); un[2 * q + 1] = pack2(d.z, d.w);
        }
    }
    // biases pre-scaled by 1/8 (8-lane reduce restores 1x)
    const float br8  = 0.125f * (b_ih[j] + b_hh[j]);
    const float bz8  = 0.125f * (b_ih[Hc + j] + b_hh[Hc + j]);
    const float bnx8 = 0.125f * b_ih[2 * Hc + j];
    const float bnh8 = 0.125f * b_hh[2 * Hc + j];

    const float* inp_b    = input + (size_t)b * Tc * Ic;
    float*       states_b = out + (size_t)b * Tc * Hc;
    float*       hT_out   = out + (size_t)Bc * Tc * Hc + (size_t)b * Hc;

    // ---- prologue: h0 = 0, stage input rows 0 and 1 ----
    float in_t1 = 0.0f;
    if (tid < Ic) {
        ibuf16[0][tid] = (_Float16)inp_b[tid];
        in_t1          = inp_b[Ic + tid];  // row 1
    }
    if (tid < Hc) { hbuf16[0][tid] = (_Float16)0.0f; hbuf32[0][tid] = 0.0f; }
    __syncthreads();

    for (int t = 0; t < Tc; ++t) {
        const int rb = t & 1;
        const int wb = rb ^ 1;

        // prefetch input row t+2 (wave 0 only)
        float in_t2 = 0.0f;
        if (tid < Ic) {
            const int tn = (t + 2 < Tc) ? (t + 2) : (Tc - 1);
            in_t2 = inp_b[(size_t)tn * Ic + tid];
        }

        const float h_old = hbuf32[rb][j];

        float ar = br8;    // r gate (x+h combined)
        float az = bz8;    // z gate (x+h combined)
        float ah = bnh8;   // n gate, hidden part
        float ax = bnx8;   // n gate, input part

        // hidden dot: 16 h values = 8 fp16 pairs, 2x ds_read_b128 (broadcast)
        const uint4* hb = reinterpret_cast<const uint4*>(&hbuf16[rb][ks * 16]);
#pragma unroll
        for (int q = 0; q < 2; ++q) {
            const uint4 hv = hb[q];
            const f16x2 p0 = __builtin_bit_cast(f16x2, hv.x);
            const f16x2 p1 = __builtin_bit_cast(f16x2, hv.y);
            const f16x2 p2 = __builtin_bit_cast(f16x2, hv.z);
            const f16x2 p3 = __builtin_bit_cast(f16x2, hv.w);
            ar = FDOT2(p0, wr[4 * q + 0], ar);
            az = FDOT2(p0, wz[4 * q + 0], az);
            ah = FDOT2(p0, wn[4 * q + 0], ah);
            ar = FDOT2(p1, wr[4 * q + 1], ar);
            az = FDOT2(p1, wz[4 * q + 1], az);
            ah = FDOT2(p1, wn[4 * q + 1], ah);
            ar = FDOT2(p2, wr[4 * q + 2], ar);
            az = FDOT2(p2, wz[4 * q + 2], az);
            ah = FDOT2(p2, wn[4 * q + 2], ah);
            ar = FDOT2(p3, wr[4 * q + 3], ar);
            az = FDOT2(p3, wz[4 * q + 3], az);
            ah = FDOT2(p3, wn[4 * q + 3], ah);
        }
        // input dot: 8 x values = 4 pairs, 1x ds_read_b128 (broadcast)
        {
            const uint4 xv = *reinterpret_cast<const uint4*>(&ibuf16[rb][ks * 8]);
            const f16x2 p0 = __builtin_bit_cast(f16x2, xv.x);
            const f16x2 p1 = __builtin_bit_cast(f16x2, xv.y);
            const f16x2 p2 = __builtin_bit_cast(f16x2, xv.z);
            const f16x2 p3 = __builtin_bit_cast(f16x2, xv.w);
            ar = FDOT2(p0, ur[0], ar);
            az = FDOT2(p0, uz[0], az);
            ax = FDOT2(p0, un[0], ax);
            ar = FDOT2(p1, ur[1], ar);
            az = FDOT2(p1, uz[1], az);
            ax = FDOT2(p1, un[1], ax);
            ar = FDOT2(p2, ur[2], ar);
            az = FDOT2(p2, uz[2], az);
            ax = FDOT2(p2, un[2], ax);
            ar = FDOT2(p3, ur[3], ar);
            az = FDOT2(p3, uz[3], az);
            ax = FDOT2(p3, un[3], ax);
        }

        // 8-lane reduce: 3 DPP levels, pure VALU
        const float arS = oct_reduce(ar);
        const float azS = oct_reduce(az);
        const float ahS = oct_reduce(ah);
        const float axS = oct_reduce(ax);

        // gates (replicated across the 8-lane group)
        const float r    = fast_sigmoid(arS);
        const float z    = fast_sigmoid(azS);
        const float n    = fast_tanh(axS + r * ahS);
        const float hnew = n + z * (h_old - n);

        // spread epilogue stores across group lanes
        if (ks == 0) hbuf32[wb][j] = hnew;
        else if (ks == 3) hbuf16[wb][j] = (_Float16)hnew;
        else if (ks == 1) states_b[(size_t)t * Hc + j] = hnew;
        else if (ks == 2) { if (t == Tc - 1) hT_out[j] = hnew; }
        if (tid < Ic) {
            ibuf16[wb][tid] = (_Float16)in_t1;
            in_t1 = in_t2;
        }
        __syncthreads();
    }
}

extern "C" void kernel_launch(void* const* d_in, const int* in_sizes, int n_in,
                              void* d_out, int out_size, void* d_ws, size_t ws_size,
                              hipStream_t stream) {
    const float* input = (const float*)d_in[0];
    const float* W_ih  = (const float*)d_in[1];
    const float* W_hh  = (const float*)d_in[2];
    const float* b_ih  = (const float*)d_in[3];
    const float* b_hh  = (const float*)d_in[4];
    float* out = (float*)d_out;
    (void)in_sizes; (void)n_in; (void)d_ws; (void)ws_size; (void)out_size;

    gru_scan_kernel<<<Bc, 1024, 0, stream>>>(input, W_ih, W_hh, b_ih, b_hh, out);
}

// Round 11
// 624.014 us; speedup vs baseline: 1.3086x; 1.3086x over previous
//
#include <hip/hip_runtime.h>

// GRU: B=256, T=1000, I=64, H=128 (3H=384).
// Round-11 PIVOT: MFMA scan. Evidence r1-r10: all scalar-FMA variants are
// VALU-issue-bound at ~700-900us because the register allocator caps arch
// VGPRs at ~0.4x budget (measured 104/84/60/44) and every demoted weight
// costs a v_accvgpr_read. MFMA consumes AGPRs natively -> the problem
// dissolves. Decomposition: 16 blocks x 16 batch rows; per step
// [16,128]@[128,384] via v_mfma_f32_16x16x32_f16 (12 MFMA/wave, K-chained)
// + fused x-projection for t+1 (6 MFMA/wave) whose accumulators become
// next step's C-init (x_proj never materialized). Gates lane-local fp32
// (r,z,hn,xn co-located by C-layout). h through LDS f16 (C-layout ->
// A-layout transpose). 1 barrier/step. fp16 numerics = r9-validated.
// Layouts (per guide §3): C/D row=(l>>4)*4+reg, col=l&15 (HW-verified);
// A: m=l&15, k=(l>>4)*8+e; B: n=l&15, k=(l>>4)*8+e.

#define Tc 1000
#define Ic 64
#define Hc 128
#define Bc 256
#define MBLK 16
#define NBLOCKS 16

typedef _Float16 half8 __attribute__((ext_vector_type(8)));
typedef float f32x4 __attribute__((ext_vector_type(4)));

#define MFMA_F16(A, B, C) __builtin_amdgcn_mfma_f32_16x16x32_f16((A), (B), (C), 0, 0, 0)

__device__ __forceinline__ float fast_sigmoid(float x) {
    return __builtin_amdgcn_rcpf(1.0f + __expf(-x));
}
__device__ __forceinline__ float fast_tanh(float x) {
    return 1.0f - 2.0f * __builtin_amdgcn_rcpf(__expf(2.0f * x) + 1.0f);
}

__global__ __launch_bounds__(512, 2) void gru_mfma_kernel(
    const float* __restrict__ input,   // [B][T][I]
    const float* __restrict__ W_ih,    // [3H][I]
    const float* __restrict__ W_hh,    // [3H][H]
    const float* __restrict__ b_ih,    // [3H]
    const float* __restrict__ b_hh,    // [3H]
    float* __restrict__ out)           // states [B][T][H] then hT [B][H]
{
    const int blk = blockIdx.x;
    const int tid = threadIdx.x;
    const int l   = tid & 63;
    const int w   = tid >> 6;    // wave 0..7
    const int ln  = l & 15;      // A-row m / B-col n offset
    const int lg  = l >> 4;      // k-group 0..3
    const int jb  = w * 16;      // wave's j-base
    const int j   = jb + ln;     // this lane's gate column / h-unit

    __shared__ __align__(16) _Float16 hbuf[2][MBLK][136];  // h(t) f16, padded
    __shared__ __align__(16) _Float16 xbuf[2][MBLK][72];   // x rows f16, padded

    // ---------- persistent B-fragments (MFMA-native registers) ----------
    // B[k][n] = W[n][k]; lane: n = j, k = kc*32 + lg*8 + e.
    half8 bh[3][4], bx[3][2];
#pragma unroll
    for (int g = 0; g < 3; ++g) {
        const float* rw = W_hh + (size_t)(g * Hc + j) * Hc;
#pragma unroll
        for (int kc = 0; kc < 4; ++kc) {
            const float* p = rw + kc * 32 + lg * 8;
            half8 f;
#pragma unroll
            for (int e = 0; e < 8; ++e) f[e] = (_Float16)p[e];
            bh[g][kc] = f;
        }
        const float* rx = W_ih + (size_t)(g * Hc + j) * Ic;
#pragma unroll
        for (int kc = 0; kc < 2; ++kc) {
            const float* p = rx + kc * 32 + lg * 8;
            half8 f;
#pragma unroll
            for (int e = 0; e < 8; ++e) f[e] = (_Float16)p[e];
            bx[g][kc] = f;
        }
    }

    const float br0 = b_ih[j] + b_hh[j];                // r bias (combined)
    const float bz0 = b_ih[Hc + j] + b_hh[Hc + j];      // z bias (combined)
    const float bnx = b_ih[2 * Hc + j];                 // n input-side bias
    const float bnh = b_hh[2 * Hc + j];                 // n hidden-side bias

    // ---------- input staging geometry ----------
    const int sm = tid >> 5;          // batch row within block
    const int sk = (tid & 31) * 2;    // k-offset (2 floats / thread)
    const float* inrow = input + (size_t)(blk * MBLK + sm) * Tc * Ic + sk;

    {   // stage x rows 0 and 1
        float2 v0 = *reinterpret_cast<const float2*>(inrow);
        float2 v1 = *reinterpret_cast<const float2*>(inrow + Ic);
        union { _Float16 h[2]; unsigned u; } p0, p1;
        p0.h[0] = (_Float16)v0.x; p0.h[1] = (_Float16)v0.y;
        p1.h[0] = (_Float16)v1.x; p1.h[1] = (_Float16)v1.y;
        *reinterpret_cast<unsigned*>(&xbuf[0][sm][sk]) = p0.u;
        *reinterpret_cast<unsigned*>(&xbuf[1][sm][sk]) = p1.u;
    }
    for (int i = tid; i < MBLK * 136; i += 512)   // h(-1) = 0
        (&hbuf[1][0][0])[i] = (_Float16)0.0f;

    float2 xpre0 = *reinterpret_cast<const float2*>(inrow + 2 * Ic);  // row 2
    float2 xpre1 = *reinterpret_cast<const float2*>(inrow + 3 * Ic);  // row 3

    __syncthreads();

    // ---------- prologue: x-projection for t=0 (C-init handoff) ----------
    f32x4 cr  = {br0, br0, br0, br0};
    f32x4 cz  = {bz0, bz0, bz0, bz0};
    f32x4 cxn = {bnx, bnx, bnx, bnx};
    {
        const _Float16* xr = &xbuf[0][ln][lg * 8];
        half8 xa0 = *reinterpret_cast<const half8*>(xr);
        half8 xa1 = *reinterpret_cast<const half8*>(xr + 32);
        cr  = MFMA_F16(xa0, bx[0][0], cr);  cr  = MFMA_F16(xa1, bx[0][1], cr);
        cz  = MFMA_F16(xa0, bx[1][0], cz);  cz  = MFMA_F16(xa1, bx[1][1], cz);
        cxn = MFMA_F16(xa0, bx[2][0], cxn); cxn = MFMA_F16(xa1, bx[2][1], cxn);
    }
    f32x4 hold = {0.f, 0.f, 0.f, 0.f};

    float* states = out;
    float* hT     = out + (size_t)Bc * Tc * Hc;

#define GRU_STEP(T_, PAR_, XPRE_)                                               \
    {                                                                           \
        __syncthreads();                                                        \
        /* h-dot: A = h(t-1) from hbuf[1-PAR], 4 K-chained MFMAs per gate */    \
        const _Float16* hrp = &hbuf[1 - (PAR_)][ln][lg * 8];                    \
        half8 ha0 = *reinterpret_cast<const half8*>(hrp);                       \
        half8 ha1 = *reinterpret_cast<const half8*>(hrp + 32);                  \
        half8 ha2 = *reinterpret_cast<const half8*>(hrp + 64);                  \
        half8 ha3 = *reinterpret_cast<const half8*>(hrp + 96);                  \
        f32x4 chn = {bnh, bnh, bnh, bnh};                                       \
        cr = MFMA_F16(ha0, bh[0][0], cr); cz = MFMA_F16(ha0, bh[1][0], cz);     \
        chn = MFMA_F16(ha0, bh[2][0], chn);                                     \
        cr = MFMA_F16(ha1, bh[0][1], cr); cz = MFMA_F16(ha1, bh[1][1], cz);     \
        chn = MFMA_F16(ha1, bh[2][1], chn);                                     \
        cr = MFMA_F16(ha2, bh[0][2], cr); cz = MFMA_F16(ha2, bh[1][2], cz);     \
        chn = MFMA_F16(ha2, bh[2][2], chn);                                     \
        cr = MFMA_F16(ha3, bh[0][3], cr); cz = MFMA_F16(ha3, bh[1][3], cz);     \
        chn = MFMA_F16(ha3, bh[2][3], chn);                                     \
        /* x-projection for t+1 into fresh accumulators (overlaps gates) */     \
        const _Float16* xrp = &xbuf[1 - (PAR_)][ln][lg * 8];                    \
        half8 xa0 = *reinterpret_cast<const half8*>(xrp);                       \
        half8 xa1 = *reinterpret_cast<const half8*>(xrp + 32);                  \
        f32x4 nr = {br0, br0, br0, br0};                                        \
        f32x4 nz = {bz0, bz0, bz0, bz0};                                        \
        f32x4 nx = {bnx, bnx, bnx, bnx};                                        \
        nr = MFMA_F16(xa0, bx[0][0], nr); nr = MFMA_F16(xa1, bx[0][1], nr);     \
        nz = MFMA_F16(xa0, bx[1][0], nz); nz = MFMA_F16(xa1, bx[1][1], nz);     \
        nx = MFMA_F16(xa0, bx[2][0], nx); nx = MFMA_F16(xa1, bx[2][1], nx);     \
        /* stage x row T_+2 (regs loaded 2 steps ago); refill with T_+4 */      \
        {                                                                       \
            union { _Float16 h[2]; unsigned u; } pk;                            \
            pk.h[0] = (_Float16)XPRE_.x; pk.h[1] = (_Float16)XPRE_.y;           \
            *reinterpret_cast<unsigned*>(&xbuf[PAR_][sm][sk]) = pk.u;           \
            const int trow = ((T_) + 4 < Tc) ? ((T_) + 4) : (Tc - 1);           \
            XPRE_ = *reinterpret_cast<const float2*>(inrow + (size_t)trow * Ic);\
        }                                                                       \
        /* gates: lane-local (C-layout co-locates r,z,hn,xn per (m,j)) */       \
        f32x4 hn;                                                               \
        _Pragma("unroll")                                                       \
        for (int i = 0; i < 4; ++i) {                                           \
            const float rg = fast_sigmoid(cr[i]);                               \
            const float zg = fast_sigmoid(cz[i]);                               \
            const float nv = fast_tanh(cxn[i] + rg * chn[i]);                   \
            hn[i] = nv + zg * (hold[i] - nv);                                   \
        }                                                                       \
        _Pragma("unroll")                                                       \
        for (int i = 0; i < 4; ++i) {                                           \
            const int m = lg * 4 + i;                                           \
            hbuf[PAR_][m][j] = (_Float16)hn[i];                                 \
            states[((size_t)(blk * MBLK + m) * Tc + (T_)) * Hc + j] = hn[i];    \
        }                                                                       \
        if ((T_) == Tc - 1) {                                                   \
            _Pragma("unroll")                                                   \
            for (int i = 0; i < 4; ++i)                                         \
                hT[(size_t)(blk * MBLK + lg * 4 + i) * Hc + j] = hn[i];         \
        }                                                                       \
        cr = nr; cz = nz; cxn = nx; hold = hn;                                  \
    }

    for (int t = 0; t < Tc; t += 2) {
        GRU_STEP(t, 0, xpre0);
        GRU_STEP(t + 1, 1, xpre1);
    }
#undef GRU_STEP
}

extern "C" void kernel_launch(void* const* d_in, const int* in_sizes, int n_in,
                              void* d_out, int out_size, void* d_ws, size_t ws_size,
                              hipStream_t stream) {
    const float* input = (const float*)d_in[0];
    const float* W_ih  = (const float*)d_in[1];
    const float* W_hh  = (const float*)d_in[2];
    const float* b_ih  = (const float*)d_in[3];
    const float* b_hh  = (const float*)d_in[4];
    float* out = (float*)d_out;
    (void)in_sizes; (void)n_in; (void)d_ws; (void)ws_size; (void)out_size;

    gru_mfma_kernel<<<NBLOCKS, 512, 0, stream>>>(input, W_ih, W_hh, b_ih, b_hh, out);
}

// Round 12
// 587.190 us; speedup vs baseline: 1.3907x; 1.0627x over previous
//
#include <hip/hip_runtime.h>

// GRU: B=256, T=1000, I=64, H=128 (3H=384).
// Round-12: r11 MFMA scan, scaled out 16->32 CUs. 32 blocks x 8 batch rows
// (MFMA M=16 tile, rows 8-15 zero-padded: MFMA count is shape-fixed, so the
// pad is free on the matrix pipe). r11 measured on-CU VALUBusy 56% with
// TRANS (exp/rcp @ 1/4 rate) = 384 cyc/SIMD/step the largest term; with
// M=8 all real C rows land in lanes<32 (4 elems each) -> redistribute
// elems 2,3 of {cr,cz,cxn,chn} to lanes>=32 via __shfl_xor(.,32) so all
// 64 lanes process 2 gate-triples: TRANS wave-insts 24->12, gate VALU
// and h/state writes halve per lane. MFMA/LDS structure = r11 (verified).

#define Tc 1000
#define Ic 64
#define Hc 128
#define Bc 256
#define MBLK 8
#define NBLOCKS 32

typedef _Float16 half8 __attribute__((ext_vector_type(8)));
typedef float f32x4 __attribute__((ext_vector_type(4)));

#define MFMA_F16(A, B, C) __builtin_amdgcn_mfma_f32_16x16x32_f16((A), (B), (C), 0, 0, 0)

__device__ __forceinline__ float fast_sigmoid(float x) {
    return __builtin_amdgcn_rcpf(1.0f + __expf(-x));
}
__device__ __forceinline__ float fast_tanh(float x) {
    return 1.0f - 2.0f * __builtin_amdgcn_rcpf(__expf(2.0f * x) + 1.0f);
}

__global__ __launch_bounds__(512, 2) void gru_mfma_kernel(
    const float* __restrict__ input,   // [B][T][I]
    const float* __restrict__ W_ih,    // [3H][I]
    const float* __restrict__ W_hh,    // [3H][H]
    const float* __restrict__ b_ih,    // [3H]
    const float* __restrict__ b_hh,    // [3H]
    float* __restrict__ out)           // states [B][T][H] then hT [B][H]
{
    const int blk = blockIdx.x;
    const int tid = threadIdx.x;
    const int l   = tid & 63;
    const int w   = tid >> 6;    // wave 0..7
    const int ln  = l & 15;      // A-row m / B-col n offset
    const int lg  = l >> 4;      // k-group 0..3
    const int j   = w * 16 + ln; // this lane's gate column / h-unit
    const bool hi = (l >= 32);

    __shared__ __align__(16) _Float16 hbuf[2][16][136];  // h(t) f16; rows 8-15 stay 0
    __shared__ __align__(16) _Float16 xbuf[2][16][72];   // x rows f16; rows 8-15 stay 0

    // ---------- persistent B-fragments (identical to r11, verified) ----------
    half8 bh[3][4], bx[3][2];
#pragma unroll
    for (int g = 0; g < 3; ++g) {
        const float* rw = W_hh + (size_t)(g * Hc + j) * Hc;
#pragma unroll
        for (int kc = 0; kc < 4; ++kc) {
            const float* p = rw + kc * 32 + lg * 8;
            half8 f;
#pragma unroll
            for (int e = 0; e < 8; ++e) f[e] = (_Float16)p[e];
            bh[g][kc] = f;
        }
        const float* rx = W_ih + (size_t)(g * Hc + j) * Ic;
#pragma unroll
        for (int kc = 0; kc < 2; ++kc) {
            const float* p = rx + kc * 32 + lg * 8;
            half8 f;
#pragma unroll
            for (int e = 0; e < 8; ++e) f[e] = (_Float16)p[e];
            bx[g][kc] = f;
        }
    }

    const float br0 = b_ih[j] + b_hh[j];
    const float bz0 = b_ih[Hc + j] + b_hh[Hc + j];
    const float bnx = b_ih[2 * Hc + j];
    const float bnh = b_hh[2 * Hc + j];

    // ---------- input staging geometry (8 real rows) ----------
    const int  sm  = tid >> 5;          // 0..15
    const int  sk  = (tid & 31) * 2;
    const bool stg = sm < MBLK;
    const float* inrow = input + (size_t)(blk * MBLK + (stg ? sm : 0)) * Tc * Ic + sk;

    // zero all of hbuf/xbuf (h(-1)=0; pad rows stay 0 forever)
    for (int i = tid; i < 2 * 16 * 136; i += 512) (&hbuf[0][0][0])[i] = (_Float16)0.0f;
    for (int i = tid; i < 2 * 16 * 72;  i += 512) (&xbuf[0][0][0])[i] = (_Float16)0.0f;
    __syncthreads();

    float2 xpre0 = {0.f, 0.f}, xpre1 = {0.f, 0.f};
    if (stg) {   // stage x rows 0,1; prefetch rows 2,3
        float2 v0 = *reinterpret_cast<const float2*>(inrow);
        float2 v1 = *reinterpret_cast<const float2*>(inrow + Ic);
        union { _Float16 h[2]; unsigned u; } p0, p1;
        p0.h[0] = (_Float16)v0.x; p0.h[1] = (_Float16)v0.y;
        p1.h[0] = (_Float16)v1.x; p1.h[1] = (_Float16)v1.y;
        *reinterpret_cast<unsigned*>(&xbuf[0][sm][sk]) = p0.u;
        *reinterpret_cast<unsigned*>(&xbuf[1][sm][sk]) = p1.u;
        xpre0 = *reinterpret_cast<const float2*>(inrow + 2 * Ic);
        xpre1 = *reinterpret_cast<const float2*>(inrow + 3 * Ic);
    }
    __syncthreads();

    // ---------- prologue: x-projection for t=0 ----------
    f32x4 cr  = {br0, br0, br0, br0};
    f32x4 cz  = {bz0, bz0, bz0, bz0};
    f32x4 cxn = {bnx, bnx, bnx, bnx};
    {
        const _Float16* xr = &xbuf[0][ln][lg * 8];
        half8 xa0 = *reinterpret_cast<const half8*>(xr);
        half8 xa1 = *reinterpret_cast<const half8*>(xr + 32);
        cr  = MFMA_F16(xa0, bx[0][0], cr);  cr  = MFMA_F16(xa1, bx[0][1], cr);
        cz  = MFMA_F16(xa0, bx[1][0], cz);  cz  = MFMA_F16(xa1, bx[1][1], cz);
        cxn = MFMA_F16(xa0, bx[2][0], cxn); cxn = MFMA_F16(xa1, bx[2][1], cxn);
    }
    float holdA = 0.f, holdB = 0.f;

    // this lane's two owned batch rows after redistribution
    const int mA = (lg & 1) * 4 + (hi ? 2 : 0);
    const int mB = mA + 1;
    float* sA  = out + (size_t)(blk * MBLK + mA) * Tc * Hc + j;   // states run-ptr
    float* sB  = out + (size_t)(blk * MBLK + mB) * Tc * Hc + j;
    float* hTp = out + (size_t)Bc * Tc * Hc;

#define GRU_STEP(T_, PAR_, XPRE_)                                               \
    {                                                                           \
        __syncthreads();                                                        \
        const _Float16* hrp = &hbuf[1 - (PAR_)][ln][lg * 8];                    \
        half8 ha0 = *reinterpret_cast<const half8*>(hrp);                       \
        half8 ha1 = *reinterpret_cast<const half8*>(hrp + 32);                  \
        half8 ha2 = *reinterpret_cast<const half8*>(hrp + 64);                  \
        half8 ha3 = *reinterpret_cast<const half8*>(hrp + 96);                  \
        f32x4 chn = {bnh, bnh, bnh, bnh};                                       \
        cr = MFMA_F16(ha0, bh[0][0], cr); cz = MFMA_F16(ha0, bh[1][0], cz);     \
        chn = MFMA_F16(ha0, bh[2][0], chn);                                     \
        cr = MFMA_F16(ha1, bh[0][1], cr); cz = MFMA_F16(ha1, bh[1][1], cz);     \
        chn = MFMA_F16(ha1, bh[2][1], chn);                                     \
        cr = MFMA_F16(ha2, bh[0][2], cr); cz = MFMA_F16(ha2, bh[1][2], cz);     \
        chn = MFMA_F16(ha2, bh[2][2], chn);                                     \
        cr = MFMA_F16(ha3, bh[0][3], cr); cz = MFMA_F16(ha3, bh[1][3], cz);     \
        chn = MFMA_F16(ha3, bh[2][3], chn);                                     \
        const _Float16* xrp = &xbuf[1 - (PAR_)][ln][lg * 8];                    \
        half8 xa0 = *reinterpret_cast<const half8*>(xrp);                       \
        half8 xa1 = *reinterpret_cast<const half8*>(xrp + 32);                  \
        f32x4 nr = {br0, br0, br0, br0};                                        \
        f32x4 nz = {bz0, bz0, bz0, bz0};                                        \
        f32x4 nx = {bnx, bnx, bnx, bnx};                                        \
        nr = MFMA_F16(xa0, bx[0][0], nr); nr = MFMA_F16(xa1, bx[0][1], nr);     \
        nz = MFMA_F16(xa0, bx[1][0], nz); nz = MFMA_F16(xa1, bx[1][1], nz);     \
        nx = MFMA_F16(xa0, bx[2][0], nx); nx = MFMA_F16(xa1, bx[2][1], nx);     \
        if (stg) {                                                              \
            union { _Float16 h[2]; unsigned u; } pk;                            \
            pk.h[0] = (_Float16)XPRE_.x; pk.h[1] = (_Float16)XPRE_.y;           \
            *reinterpret_cast<unsigned*>(&xbuf[PAR_][sm][sk]) = pk.u;           \
            const int trow = ((T_) + 4 < Tc) ? ((T_) + 4) : (Tc - 1);           \
            XPRE_ = *reinterpret_cast<const float2*>(inrow + (size_t)trow * Ic);\
        }                                                                       \
        /* redistribute elems 2,3 to the upper half-wave (8 bpermutes) */       \
        const float tR2 = __shfl_xor(cr[2], 32),  tR3 = __shfl_xor(cr[3], 32);  \
        const float tZ2 = __shfl_xor(cz[2], 32),  tZ3 = __shfl_xor(cz[3], 32);  \
        const float tX2 = __shfl_xor(cxn[2], 32), tX3 = __shfl_xor(cxn[3], 32); \
        const float tH2 = __shfl_xor(chn[2], 32), tH3 = __shfl_xor(chn[3], 32); \
        const float aR = hi ? tR2 : cr[0],  bR = hi ? tR3 : cr[1];              \
        const float aZ = hi ? tZ2 : cz[0],  bZ = hi ? tZ3 : cz[1];              \
        const float aX = hi ? tX2 : cxn[0], bX = hi ? tX3 : cxn[1];             \
        const float aH = hi ? tH2 : chn[0], bH = hi ? tH3 : chn[1];             \
        const float rgA = fast_sigmoid(aR), zgA = fast_sigmoid(aZ);             \
        const float nvA = fast_tanh(aX + rgA * aH);                             \
        const float hA  = nvA + zgA * (holdA - nvA);                            \
        const float rgB = fast_sigmoid(bR), zgB = fast_sigmoid(bZ);             \
        const float nvB = fast_tanh(bX + rgB * bH);                             \
        const float hB  = nvB + zgB * (holdB - nvB);                            \
        hbuf[PAR_][mA][j] = (_Float16)hA;                                       \
        hbuf[PAR_][mB][j] = (_Float16)hB;                                       \
        *sA = hA; sA += Hc;                                                     \
        *sB = hB; sB += Hc;                                                     \
        if ((T_) == Tc - 1) {                                                   \
            hTp[(size_t)(blk * MBLK + mA) * Hc + j] = hA;                       \
            hTp[(size_t)(blk * MBLK + mB) * Hc + j] = hB;                       \
        }                                                                       \
        cr = nr; cz = nz; cxn = nx; holdA = hA; holdB = hB;                     \
    }

    for (int t = 0; t < Tc; t += 2) {
        GRU_STEP(t, 0, xpre0);
        GRU_STEP(t + 1, 1, xpre1);
    }
#undef GRU_STEP
}

extern "C" void kernel_launch(void* const* d_in, const int* in_sizes, int n_in,
                              void* d_out, int out_size, void* d_ws, size_t ws_size,
                              hipStream_t stream) {
    const float* input = (const float*)d_in[0];
    const float* W_ih  = (const float*)d_in[1];
    const float* W_hh  = (const float*)d_in[2];
    const float* b_ih  = (const float*)d_in[3];
    const float* b_hh  = (const float*)d_in[4];
    float* out = (float*)d_out;
    (void)in_sizes; (void)n_in; (void)d_ws; (void)ws_size; (void)out_size;

    gru_mfma_kernel<<<NBLOCKS, 512, 0, stream>>>(input, W_ih, W_hh, b_ih, b_hh, out);
}